// Round 1
// baseline (1748.374 us; speedup 1.0000x reference)
//
#include <hip/hip_runtime.h>
#include <stdint.h>

constexpr int kB = 8192;
constexpr int kD = 512;
constexpr int kH = 16384;
constexpr int kO = 1000;

// ---------------------------------------------------------------------------
// ws layout:
//   [0, 64KB)      : unsigned long long best[kB]   (packed minkey<<32 | hidx)
//   [64KB, 128KB)  : float w2[kH]
// ---------------------------------------------------------------------------

__global__ __launch_bounds__(256) void init_best_kernel(unsigned long long* __restrict__ best) {
    int i = blockIdx.x * 256 + threadIdx.x;
    if (i < kB) best[i] = ~0ULL;
}

// One wave per row of W: w2[h] = sum_k W[h][k]^2
__global__ __launch_bounds__(256) void w2_kernel(const float* __restrict__ W,
                                                 float* __restrict__ w2) {
    int lane = threadIdx.x & 63;
    int wv   = threadIdx.x >> 6;            // 0..3
    int row  = blockIdx.x * 4 + wv;
    const float4* Wr = reinterpret_cast<const float4*>(W + (size_t)row * kD);
    float s = 0.f;
#pragma unroll
    for (int i = 0; i < 2; ++i) {           // 512 floats = 128 float4 / 64 lanes
        float4 v = Wr[lane + i * 64];
        s += v.x * v.x + v.y * v.y + v.z * v.z + v.w * v.w;
    }
#pragma unroll
    for (int off = 32; off; off >>= 1) s += __shfl_xor(s, off, 64);
    if (lane == 0) w2[row] = s;
}

// Fused fp32 GEMM (x @ W^T) + per-row argmin of score = w2[h] - 2*dot.
// Block tile 128(b) x 128(h), BK=16, 256 threads, 8x8 micro-tile.
__global__ __launch_bounds__(256) void gemm_argmin_kernel(
    const float* __restrict__ x, const float* __restrict__ W,
    const float* __restrict__ w2, unsigned long long* __restrict__ best)
{
    __shared__ __align__(16) float As[16][132];   // [k][m], pad->16B-aligned frags
    __shared__ __align__(16) float Bs[16][132];   // [k][n]

    const int tid = threadIdx.x;
    const int tx = tid & 15;      // n-dim thread coord
    const int ty = tid >> 4;      // m-dim thread coord
    const int bm0 = blockIdx.y * 128;
    const int hn0 = blockIdx.x * 128;

    float acc[8][8];
#pragma unroll
    for (int i = 0; i < 8; ++i)
#pragma unroll
        for (int j = 0; j < 8; ++j) acc[i][j] = 0.f;

    for (int kt = 0; kt < kD; kt += 16) {
        // stage tiles: 128 rows x 16 k each, transposed into [k][row]
#pragma unroll
        for (int l = 0; l < 2; ++l) {
            int q   = tid + l * 256;          // 0..511 quad id
            int row = q >> 2;
            int kq  = (q & 3) * 4;
            float4 av = *reinterpret_cast<const float4*>(
                x + (size_t)(bm0 + row) * kD + kt + kq);
            As[kq + 0][row] = av.x;
            As[kq + 1][row] = av.y;
            As[kq + 2][row] = av.z;
            As[kq + 3][row] = av.w;
            float4 bv = *reinterpret_cast<const float4*>(
                W + (size_t)(hn0 + row) * kD + kt + kq);
            Bs[kq + 0][row] = bv.x;
            Bs[kq + 1][row] = bv.y;
            Bs[kq + 2][row] = bv.z;
            Bs[kq + 3][row] = bv.w;
        }
        __syncthreads();
#pragma unroll
        for (int kk = 0; kk < 16; ++kk) {
            float a[8], b[8];
            *(float4*)&a[0] = *(const float4*)&As[kk][ty * 8 + 0];
            *(float4*)&a[4] = *(const float4*)&As[kk][ty * 8 + 4];
            *(float4*)&b[0] = *(const float4*)&Bs[kk][tx * 8 + 0];
            *(float4*)&b[4] = *(const float4*)&Bs[kk][tx * 8 + 4];
#pragma unroll
            for (int i = 0; i < 8; ++i)
#pragma unroll
                for (int j = 0; j < 8; ++j)
                    acc[i][j] = fmaf(a[i], b[j], acc[i][j]);
        }
        __syncthreads();
    }

    // epilogue: score = w2 - 2*dot ; per-row argmin (tie -> smallest h)
    float w2v[8];
#pragma unroll
    for (int j = 0; j < 8; ++j) w2v[j] = w2[hn0 + tx * 8 + j];

#pragma unroll
    for (int i = 0; i < 8; ++i) {
        float bestv = 3.0e38f;
        int   besth = 0;
#pragma unroll
        for (int j = 0; j < 8; ++j) {
            float s = fmaf(-2.f, acc[i][j], w2v[j]);
            if (s < bestv) { bestv = s; besth = hn0 + tx * 8 + j; }
        }
        // reduce across the 16 tx lanes (lane = (ty&3)*16 + tx within wave)
#pragma unroll
        for (int off = 1; off < 16; off <<= 1) {
            float ov = __shfl_xor(bestv, off, 64);
            int   oh = __shfl_xor(besth, off, 64);
            if (ov < bestv || (ov == bestv && oh < besth)) { bestv = ov; besth = oh; }
        }
        if (tx == 0) {
            unsigned u = __float_as_uint(bestv);
            u ^= (unsigned)(((int)u >> 31)) | 0x80000000u;  // monotone key
            unsigned long long key =
                ((unsigned long long)u << 32) | (unsigned)besth;
            atomicMin(&best[bm0 + ty * 8 + i], key);
        }
    }
}

// output[b] = G_fwd[:, win], recos[b] = G_rev[:, win], winners as float
__global__ __launch_bounds__(256) void gather_kernel(
    const unsigned long long* __restrict__ best,
    const float* __restrict__ Gf, const float* __restrict__ Gr,
    float* __restrict__ out)
{
    int b = blockIdx.x;
    int idx = (int)(unsigned)(best[b] & 0xFFFFFFFFu);
    float* out0 = out;                          // (B, O)
    float* out1 = out + (size_t)kB * kO;        // (B, D)
    float* outw = out + (size_t)kB * (kO + kD); // (B,)
    for (int o = threadIdx.x; o < kO; o += 256)
        out0[(size_t)b * kO + o] = Gf[(size_t)o * kH + idx];
    for (int d = threadIdx.x; d < kD; d += 256)
        out1[(size_t)b * kD + d] = Gr[(size_t)d * kH + idx];
    if (threadIdx.x == 0) outw[b] = (float)idx;
}

extern "C" void kernel_launch(void* const* d_in, const int* in_sizes, int n_in,
                              void* d_out, int out_size, void* d_ws, size_t ws_size,
                              hipStream_t stream) {
    const float* x  = (const float*)d_in[0];
    const float* W  = (const float*)d_in[1];
    const float* Gf = (const float*)d_in[2];
    const float* Gr = (const float*)d_in[3];
    float* out = (float*)d_out;

    unsigned long long* best = (unsigned long long*)d_ws;
    float* w2 = (float*)((char*)d_ws + (size_t)kB * sizeof(unsigned long long));

    hipLaunchKernelGGL(init_best_kernel, dim3(kB / 256), dim3(256), 0, stream, best);
    hipLaunchKernelGGL(w2_kernel, dim3(kH / 4), dim3(256), 0, stream, W, w2);
    hipLaunchKernelGGL(gemm_argmin_kernel, dim3(kH / 128, kB / 128), dim3(256), 0, stream,
                       x, W, w2, best);
    hipLaunchKernelGGL(gather_kernel, dim3(kB), dim3(256), 0, stream, best, Gf, Gr, out);
}

// Round 2
// 764.098 us; speedup vs baseline: 2.2882x; 2.2882x over previous
//
#include <hip/hip_runtime.h>
#include <stdint.h>

constexpr int kB = 8192;
constexpr int kD = 512;
constexpr int kH = 16384;
constexpr int kO = 1000;
constexpr int kNHB = kH / 128;          // 128 h-blocks
constexpr float kMargin = 1.0e-2f;      // certification margin (score units)

typedef _Float16 half8v __attribute__((ext_vector_type(8)));
typedef float float4v __attribute__((ext_vector_type(4)));

// ---------------------------------------------------------------------------
// ws layout (bytes):
//   OFF_XHI = 0          : f16 x_hi [8192*512]        (8 MB)
//   OFF_XLO = 8 MB       : f16 x_lo                    (8 MB)
//   OFF_WHI = 16 MB      : f16 w_hi [16384*512]       (16 MB)
//   OFF_WLO = 32 MB      : f16 w_lo                   (16 MB)
//   OFF_W2  = 48 MB      : f32 w2 [16384]             (64 KB)
//   OFF_WIN = +64KB      : int winners [8192]         (32 KB)
//   OFF_BT  = +32KB      : ulonglong2 blocktop [8192][128]  (16 MB)
// total ~64.1 MB
// ---------------------------------------------------------------------------
constexpr size_t OFF_XHI = 0;
constexpr size_t OFF_XLO = OFF_XHI + (size_t)kB * kD * 2;
constexpr size_t OFF_WHI = OFF_XLO + (size_t)kB * kD * 2;
constexpr size_t OFF_WLO = OFF_WHI + (size_t)kH * kD * 2;
constexpr size_t OFF_W2  = OFF_WLO + (size_t)kH * kD * 2;
constexpr size_t OFF_WIN = OFF_W2 + (size_t)kH * 4;
constexpr size_t OFF_BT  = OFF_WIN + (size_t)kB * 4 + 32768 - (size_t)kB * 4; // pad to 32KB
// (OFF_BT is 16B aligned)

__device__ inline unsigned long long packkey(float s, int h) {
    unsigned u = __float_as_uint(s);
    u ^= (u & 0x80000000u) ? 0xFFFFFFFFu : 0x80000000u;
    return ((unsigned long long)u << 32) | (unsigned)h;
}
__device__ inline float unpacks(unsigned long long k) {
    unsigned u = (unsigned)(k >> 32);
    u ^= (u & 0x80000000u) ? 0x80000000u : 0xFFFFFFFFu;
    return __uint_as_float(u);
}
__device__ inline unsigned long long shfl_xor_u64(unsigned long long v, int m) {
    unsigned lo = (unsigned)v, hi = (unsigned)(v >> 32);
    lo = __shfl_xor(lo, m, 64);
    hi = __shfl_xor(hi, m, 64);
    return ((unsigned long long)hi << 32) | lo;
}
__device__ inline unsigned long long u64min(unsigned long long a, unsigned long long b) {
    return a < b ? a : b;
}

template <typename T>
__device__ inline void gload_lds16(const T* g, T* l) {
    __builtin_amdgcn_global_load_lds(
        (const __attribute__((address_space(1))) uint32_t*)g,
        (__attribute__((address_space(3))) uint32_t*)l, 16, 0, 0);
}

// --------------------------- split: f32 -> f16 hi/lo ------------------------
__global__ __launch_bounds__(256) void split_kernel(const float* __restrict__ src,
                                                    _Float16* __restrict__ hi,
                                                    _Float16* __restrict__ lo) {
    size_t i = (size_t)blockIdx.x * 256 + threadIdx.x;   // 8 elems per thread
    const float4* s4 = reinterpret_cast<const float4*>(src);
    float4 a = s4[i * 2], b = s4[i * 2 + 1];
    float v[8] = {a.x, a.y, a.z, a.w, b.x, b.y, b.z, b.w};
    half8v h, l;
#pragma unroll
    for (int e = 0; e < 8; ++e) {
        _Float16 hh = (_Float16)v[e];
        h[e] = hh;
        l[e] = (_Float16)(v[e] - (float)hh);
    }
    *reinterpret_cast<half8v*>(hi + i * 8) = h;
    *reinterpret_cast<half8v*>(lo + i * 8) = l;
}

// --------------------------- w2 (exact fp32, round-1 order) -----------------
__global__ __launch_bounds__(256) void w2_kernel(const float* __restrict__ W,
                                                 float* __restrict__ w2) {
    int lane = threadIdx.x & 63;
    int wv   = threadIdx.x >> 6;
    int row  = blockIdx.x * 4 + wv;
    const float4* Wr = reinterpret_cast<const float4*>(W + (size_t)row * kD);
    float s = 0.f;
#pragma unroll
    for (int i = 0; i < 2; ++i) {
        float4 v = Wr[lane + i * 64];
        s += v.x * v.x + v.y * v.y + v.z * v.z + v.w * v.w;
    }
#pragma unroll
    for (int off = 32; off; off >>= 1) s += __shfl_xor(s, off, 64);
    if (lane == 0) w2[row] = s;
}

// --------------------------- MFMA GEMM + per-block top2 ---------------------
// 128x128 tile, BK=32, 4 waves (2x2), 3-product split-f16, double-buffered LDS.
__global__ __launch_bounds__(256) void gemm_argmin_mfma(
    const _Float16* __restrict__ xhi, const _Float16* __restrict__ xlo,
    const _Float16* __restrict__ whi, const _Float16* __restrict__ wlo,
    const float* __restrict__ w2, ulonglong2* __restrict__ blocktop)
{
    __shared__ _Float16 sm[2][4][4096];   // [buf][tile: Ah,Al,Bh,Bl][128*32]

    const int tid  = threadIdx.x;
    const int lane = tid & 63;
    const int wv   = tid >> 6;
    const int wr   = wv >> 1, wc = wv & 1;

    // XCD-aware swizzle (8192 % 8 == 0 -> simple bijection)
    int bid = blockIdx.x;
    int swz = (bid & 7) * (8192 / 8) + (bid >> 3);
    const int hb  = swz & 127;
    const int mb  = swz >> 7;
    const int bm0 = mb * 128, hn0 = hb * 128;

    float4v acc[4][4];
#pragma unroll
    for (int i = 0; i < 4; ++i)
#pragma unroll
        for (int j = 0; j < 4; ++j) acc[i][j] = (float4v){0.f, 0.f, 0.f, 0.f};

    const int aoff = (wr * 64 + (lane & 15)) * 32 + (lane >> 4) * 8;
    const int boff = (wc * 64 + (lane & 15)) * 32 + (lane >> 4) * 8;

    const int grow = lane >> 2;       // 4 lanes per row (16B each)
    const int gk   = (lane & 3) * 8;  // f16 elems

    auto STAGE = [&](int bf, int step) {
        const int kt = step * 32;
#pragma unroll
        for (int h2 = 0; h2 < 2; ++h2) {
            const int r0 = wv * 32 + h2 * 16;   // wave-uniform
            gload_lds16(xhi + (size_t)(bm0 + r0 + grow) * kD + kt + gk, &sm[bf][0][r0 * 32]);
            gload_lds16(xlo + (size_t)(bm0 + r0 + grow) * kD + kt + gk, &sm[bf][1][r0 * 32]);
            gload_lds16(whi + (size_t)(hn0 + r0 + grow) * kD + kt + gk, &sm[bf][2][r0 * 32]);
            gload_lds16(wlo + (size_t)(hn0 + r0 + grow) * kD + kt + gk, &sm[bf][3][r0 * 32]);
        }
    };
    auto COMPUTE = [&](int bf) {
        half8v bh[4], bl[4];
#pragma unroll
        for (int j = 0; j < 4; ++j) {
            bh[j] = *reinterpret_cast<const half8v*>(&sm[bf][2][boff + j * 512]);
            bl[j] = *reinterpret_cast<const half8v*>(&sm[bf][3][boff + j * 512]);
        }
#pragma unroll
        for (int i = 0; i < 4; ++i) {
            half8v ah = *reinterpret_cast<const half8v*>(&sm[bf][0][aoff + i * 512]);
            half8v al = *reinterpret_cast<const half8v*>(&sm[bf][1][aoff + i * 512]);
#pragma unroll
            for (int j = 0; j < 4; ++j) {
                acc[i][j] = __builtin_amdgcn_mfma_f32_16x16x32_f16(ah, bh[j], acc[i][j], 0, 0, 0);
                acc[i][j] = __builtin_amdgcn_mfma_f32_16x16x32_f16(al, bh[j], acc[i][j], 0, 0, 0);
                acc[i][j] = __builtin_amdgcn_mfma_f32_16x16x32_f16(ah, bl[j], acc[i][j], 0, 0, 0);
            }
        }
    };

    STAGE(0, 0);
    __syncthreads();
#pragma unroll
    for (int t = 0; t < 16; t += 2) {
        if (t + 1 < 16) STAGE(1, t + 1);
        COMPUTE(0);
        __syncthreads();
        if (t + 2 < 16) STAGE(0, t + 2);
        COMPUTE(1);
        __syncthreads();
    }

    // ---------------- epilogue: per-row top2 over this block's 128 cols ------
    unsigned long long* top2p = reinterpret_cast<unsigned long long*>(&sm[0][0][0]); // [128][2][2]
    float w2v[4];
#pragma unroll
    for (int j = 0; j < 4; ++j) w2v[j] = w2[hn0 + wc * 64 + j * 16 + (lane & 15)];

#pragma unroll
    for (int i = 0; i < 4; ++i) {
#pragma unroll
        for (int r = 0; r < 4; ++r) {
            unsigned long long k1 = ~0ull, k2 = ~0ull;
#pragma unroll
            for (int j = 0; j < 4; ++j) {
                float s = fmaf(-2.f, acc[i][j][r], w2v[j]);
                unsigned long long key = packkey(s, hn0 + wc * 64 + j * 16 + (lane & 15));
                if (key < k1) { k2 = k1; k1 = key; }
                else if (key < k2) { k2 = key; }
            }
#pragma unroll
            for (int m = 1; m < 16; m <<= 1) {
                unsigned long long o1 = shfl_xor_u64(k1, m);
                unsigned long long o2 = shfl_xor_u64(k2, m);
                unsigned long long n1 = u64min(k1, o1);
                unsigned long long mx = k1 < o1 ? o1 : k1;
                unsigned long long mn = u64min(k2, o2);
                k1 = n1;
                k2 = u64min(mx, mn);
            }
            if ((lane & 15) == 0) {
                int rl = wr * 64 + i * 16 + (lane >> 4) * 4 + r;
                top2p[(rl * 2 + wc) * 2 + 0] = k1;
                top2p[(rl * 2 + wc) * 2 + 1] = k2;
            }
        }
    }
    __syncthreads();
    if (tid < 128) {
        unsigned long long a1 = top2p[(tid * 2 + 0) * 2 + 0];
        unsigned long long a2 = top2p[(tid * 2 + 0) * 2 + 1];
        unsigned long long b1 = top2p[(tid * 2 + 1) * 2 + 0];
        unsigned long long b2 = top2p[(tid * 2 + 1) * 2 + 1];
        unsigned long long r1 = u64min(a1, b1);
        unsigned long long mx = a1 < b1 ? b1 : a1;
        unsigned long long r2 = u64min(mx, u64min(a2, b2));
        blocktop[(size_t)(bm0 + tid) * kNHB + hb] = (ulonglong2){r1, r2};
    }
}

// --------------------------- rescan: certify or exact fp32 ------------------
__global__ __launch_bounds__(256) void rescan_kernel(
    const float* __restrict__ x, const float* __restrict__ W,
    const float* __restrict__ w2, const ulonglong2* __restrict__ blocktop,
    int* __restrict__ winners)
{
    const int tid = threadIdx.x;
    const int b = blockIdx.x;
    __shared__ float xs[kD];
    __shared__ unsigned long long red[256];
    __shared__ unsigned long long sv1, sv2;
    __shared__ unsigned char cand[kNHB];

    if (tid < 128)
        reinterpret_cast<float4*>(xs)[tid] =
            reinterpret_cast<const float4*>(x + (size_t)b * kD)[tid];

    ulonglong2 t12;
    if (tid < kNHB) t12 = blocktop[(size_t)b * kNHB + tid];
    else            t12 = (ulonglong2){~0ull, ~0ull};

    red[tid] = (tid < kNHB) ? t12.x : ~0ull;
    __syncthreads();
    for (int s = 128; s > 0; s >>= 1) {
        if (tid < s) red[tid] = u64min(red[tid], red[tid + s]);
        __syncthreads();
    }
    if (tid == 0) sv1 = red[0];
    __syncthreads();
    const unsigned long long v1k = sv1;
    const float v1s = unpacks(v1k);
    const int b1hb = ((int)(unsigned)(v1k & 0xFFFFFFFFu)) >> 7;

    red[tid] = (tid < kNHB) ? ((tid == b1hb) ? t12.y : t12.x) : ~0ull;
    __syncthreads();
    for (int s = 128; s > 0; s >>= 1) {
        if (tid < s) red[tid] = u64min(red[tid], red[tid + s]);
        __syncthreads();
    }
    if (tid == 0) sv2 = red[0];
    __syncthreads();
    const float v2s = unpacks(sv2);

    if (v2s - v1s > kMargin) {          // certified (uniform branch)
        if (tid == 0) winners[b] = (int)(unsigned)(v1k & 0xFFFFFFFFu);
        return;
    }

    // uncertain: exact fp32 scan of candidate blocks (same order as round 1)
    if (tid < kNHB) cand[tid] = (unpacks(t12.x) <= v1s + kMargin) ? 1 : 0;
    __syncthreads();

    unsigned long long bestk = ~0ull;
    for (int hb = 0; hb < kNHB; ++hb) {
        if (!cand[hb]) continue;
        if (tid < 128) {
            int h = hb * 128 + tid;
            const float4* wr = reinterpret_cast<const float4*>(W + (size_t)h * kD);
            float dot = 0.f;
            for (int k = 0; k < kD / 4; ++k) {
                float4 wv = wr[k];
                dot = fmaf(xs[k * 4 + 0], wv.x, dot);
                dot = fmaf(xs[k * 4 + 1], wv.y, dot);
                dot = fmaf(xs[k * 4 + 2], wv.z, dot);
                dot = fmaf(xs[k * 4 + 3], wv.w, dot);
            }
            float s = fmaf(-2.f, dot, w2[h]);
            bestk = u64min(bestk, packkey(s, h));
        }
    }
    red[tid] = bestk;
    __syncthreads();
    for (int s = 128; s > 0; s >>= 1) {
        if (tid < s) red[tid] = u64min(red[tid], red[tid + s]);
        __syncthreads();
    }
    if (tid == 0) winners[b] = (int)(unsigned)(red[0] & 0xFFFFFFFFu);
}

// --------------------------- gather epilogue --------------------------------
__global__ __launch_bounds__(256) void gather_kernel(
    const int* __restrict__ winners,
    const float* __restrict__ Gf, const float* __restrict__ Gr,
    float* __restrict__ out)
{
    int b = blockIdx.x;
    int idx = winners[b];
    float* out0 = out;                            // (B, O)
    float* out1 = out + (size_t)kB * kO;          // (B, D)
    float* outw = out + (size_t)kB * (kO + kD);   // (B,)
    for (int o = threadIdx.x; o < kO; o += 256)
        out0[(size_t)b * kO + o] = Gf[(size_t)o * kH + idx];
    for (int d = threadIdx.x; d < kD; d += 256)
        out1[(size_t)b * kD + d] = Gr[(size_t)d * kH + idx];
    if (threadIdx.x == 0) outw[b] = (float)idx;
}

extern "C" void kernel_launch(void* const* d_in, const int* in_sizes, int n_in,
                              void* d_out, int out_size, void* d_ws, size_t ws_size,
                              hipStream_t stream) {
    const float* x  = (const float*)d_in[0];
    const float* W  = (const float*)d_in[1];
    const float* Gf = (const float*)d_in[2];
    const float* Gr = (const float*)d_in[3];
    float* out = (float*)d_out;

    char* ws = (char*)d_ws;
    _Float16* xhi = (_Float16*)(ws + OFF_XHI);
    _Float16* xlo = (_Float16*)(ws + OFF_XLO);
    _Float16* whi = (_Float16*)(ws + OFF_WHI);
    _Float16* wlo = (_Float16*)(ws + OFF_WLO);
    float* w2 = (float*)(ws + OFF_W2);
    int* winners = (int*)(ws + OFF_WIN);
    ulonglong2* blocktop = (ulonglong2*)(ws + OFF_BT);

    hipLaunchKernelGGL(split_kernel, dim3(kB * kD / (256 * 8)), dim3(256), 0, stream, x, xhi, xlo);
    hipLaunchKernelGGL(split_kernel, dim3(kH * kD / (256 * 8)), dim3(256), 0, stream, W, whi, wlo);
    hipLaunchKernelGGL(w2_kernel, dim3(kH / 4), dim3(256), 0, stream, W, w2);
    hipLaunchKernelGGL(gemm_argmin_mfma, dim3(8192), dim3(256), 0, stream,
                       xhi, xlo, whi, wlo, w2, blocktop);
    hipLaunchKernelGGL(rescan_kernel, dim3(kB), dim3(256), 0, stream, x, W, w2, blocktop, winners);
    hipLaunchKernelGGL(gather_kernel, dim3(kB), dim3(256), 0, stream, winners, Gf, Gr, out);
}

// Round 3
// 689.963 us; speedup vs baseline: 2.5340x; 1.1074x over previous
//
#include <hip/hip_runtime.h>
#include <stdint.h>

constexpr int kB = 8192;
constexpr int kD = 512;
constexpr int kH = 16384;
constexpr int kO = 1000;
constexpr int kNHB = kH / 128;          // 128 h-blocks
constexpr float kMargin = 0.08f;        // > 2*e_max (e_max ~0.025 for 2-term split)

typedef _Float16 half8v __attribute__((ext_vector_type(8)));
typedef _Float16 half4v __attribute__((ext_vector_type(4)));
typedef float float4v __attribute__((ext_vector_type(4)));

// ---------------------------------------------------------------------------
// ws layout (bytes):
//   OFF_XHI : f16 x_hi [8192*512]   (8 MB)
//   OFF_XLO : f16 x_lo              (8 MB)
//   OFF_WHI : f16 w_hi [16384*512]  (16 MB)
//   OFF_W2  : f32 w2 [16384]        (64 KB)
//   OFF_BT  : ulonglong2 blocktop [8192][128]  (16 MB)
// ---------------------------------------------------------------------------
constexpr size_t OFF_XHI = 0;
constexpr size_t OFF_XLO = OFF_XHI + (size_t)kB * kD * 2;
constexpr size_t OFF_WHI = OFF_XLO + (size_t)kB * kD * 2;
constexpr size_t OFF_W2  = OFF_WHI + (size_t)kH * kD * 2;
constexpr size_t OFF_BT  = OFF_W2 + 65536;

__device__ inline unsigned long long packkey(float s, int h) {
    unsigned u = __float_as_uint(s);
    u ^= (u & 0x80000000u) ? 0xFFFFFFFFu : 0x80000000u;
    return ((unsigned long long)u << 32) | (unsigned)h;
}
__device__ inline float unpacks(unsigned long long k) {
    unsigned u = (unsigned)(k >> 32);
    u ^= (u & 0x80000000u) ? 0x80000000u : 0xFFFFFFFFu;
    return __uint_as_float(u);
}
__device__ inline unsigned long long shfl_xor_u64(unsigned long long v, int m) {
    unsigned lo = (unsigned)v, hi = (unsigned)(v >> 32);
    lo = __shfl_xor(lo, m, 64);
    hi = __shfl_xor(hi, m, 64);
    return ((unsigned long long)hi << 32) | lo;
}
__device__ inline unsigned long long u64min(unsigned long long a, unsigned long long b) {
    return a < b ? a : b;
}

template <typename T>
__device__ inline void gload_lds16(const T* g, T* l) {
    __builtin_amdgcn_global_load_lds(
        (const __attribute__((address_space(1))) uint32_t*)g,
        (__attribute__((address_space(3))) uint32_t*)l, 16, 0, 0);
}

// --------------------------- split x: f32 -> f16 hi/lo ----------------------
__global__ __launch_bounds__(256) void split_kernel(const float* __restrict__ src,
                                                    _Float16* __restrict__ hi,
                                                    _Float16* __restrict__ lo) {
    size_t i = (size_t)blockIdx.x * 256 + threadIdx.x;   // 8 elems per thread
    const float4* s4 = reinterpret_cast<const float4*>(src);
    float4 a = s4[i * 2], b = s4[i * 2 + 1];
    float v[8] = {a.x, a.y, a.z, a.w, b.x, b.y, b.z, b.w};
    half8v h, l;
#pragma unroll
    for (int e = 0; e < 8; ++e) {
        _Float16 hh = (_Float16)v[e];
        h[e] = hh;
        l[e] = (_Float16)(v[e] - (float)hh);
    }
    *reinterpret_cast<half8v*>(hi + i * 8) = h;
    *reinterpret_cast<half8v*>(lo + i * 8) = l;
}

// ------------------ split W (hi only) + fused w2 (round-1 order) ------------
__global__ __launch_bounds__(256) void splitw_w2_kernel(const float* __restrict__ W,
                                                        _Float16* __restrict__ whi,
                                                        float* __restrict__ w2) {
    int lane = threadIdx.x & 63;
    int wv   = threadIdx.x >> 6;
    int row  = blockIdx.x * 4 + wv;
    const float4* Wr = reinterpret_cast<const float4*>(W + (size_t)row * kD);
    float s = 0.f;
#pragma unroll
    for (int i = 0; i < 2; ++i) {
        float4 v = Wr[lane + i * 64];
        s += v.x * v.x + v.y * v.y + v.z * v.z + v.w * v.w;
        half4v h = {(_Float16)v.x, (_Float16)v.y, (_Float16)v.z, (_Float16)v.w};
        *reinterpret_cast<half4v*>(whi + (size_t)row * kD + i * 256 + lane * 4) = h;
    }
#pragma unroll
    for (int off = 32; off; off >>= 1) s += __shfl_xor(s, off, 64);
    if (lane == 0) w2[row] = s;
}

// --------------------------- MFMA GEMM + per-block top2 ---------------------
// 128x128 tile, BK=32, 4 waves (2x2), 2-product split-f16, dbuf, XOR-swizzled LDS.
__global__ __launch_bounds__(256) void gemm_argmin_mfma(
    const _Float16* __restrict__ xhi, const _Float16* __restrict__ xlo,
    const _Float16* __restrict__ whi,
    const float* __restrict__ w2, ulonglong2* __restrict__ blocktop)
{
    __shared__ __align__(16) _Float16 sm[2][3][4096];   // [buf][Ah,Al,Bh][128 rows * 32]

    const int tid  = threadIdx.x;
    const int lane = tid & 63;
    const int wv   = tid >> 6;
    const int wr   = wv >> 1, wc = wv & 1;

    // XCD-aware swizzle (8192 % 8 == 0 -> bijective)
    int bid = blockIdx.x;
    int swz = (bid & 7) * (8192 / 8) + (bid >> 3);
    const int hb  = swz & 127;
    const int mb  = swz >> 7;
    const int bm0 = mb * 128, hn0 = hb * 128;

    float4v acc[4][4];
#pragma unroll
    for (int i = 0; i < 4; ++i)
#pragma unroll
        for (int j = 0; j < 4; ++j) acc[i][j] = (float4v){0.f, 0.f, 0.f, 0.f};

    // staging coords: each gload_lds16 stages 16 rows x 32 f16 (64 lanes x 16B)
    const int srow = lane >> 2;        // row within 16-row chunk
    const int sch  = lane & 3;         // dest 16B chunk within 64B row

    auto STAGE = [&](int bf, int step) {
        const int kt = step * 32;
#pragma unroll
        for (int h2 = 0; h2 < 2; ++h2) {
            const int r0 = wv * 32 + h2 * 16;            // wave-uniform
            const int r  = r0 + srow;                    // row within 128-tile
            const int cs = sch ^ ((r >> 1) & 3);         // pre-swizzled source chunk
            const size_t ka = (size_t)kt + cs * 8;
            gload_lds16(xhi + (size_t)(bm0 + r) * kD + ka, &sm[bf][0][r0 * 32]);
            gload_lds16(xlo + (size_t)(bm0 + r) * kD + ka, &sm[bf][1][r0 * 32]);
            gload_lds16(whi + (size_t)(hn0 + r) * kD + ka, &sm[bf][2][r0 * 32]);
        }
    };
    auto COMPUTE = [&](int bf) {
        half8v bh[4];
#pragma unroll
        for (int j = 0; j < 4; ++j) {
            const int row = wc * 64 + j * 16 + (lane & 15);
            const int cs  = (lane >> 4) ^ ((row >> 1) & 3);
            bh[j] = *reinterpret_cast<const half8v*>(&sm[bf][2][row * 32 + cs * 8]);
        }
#pragma unroll
        for (int i = 0; i < 4; ++i) {
            const int arow = wr * 64 + i * 16 + (lane & 15);
            const int acs  = (lane >> 4) ^ ((arow >> 1) & 3);
            half8v ah = *reinterpret_cast<const half8v*>(&sm[bf][0][arow * 32 + acs * 8]);
            half8v al = *reinterpret_cast<const half8v*>(&sm[bf][1][arow * 32 + acs * 8]);
#pragma unroll
            for (int j = 0; j < 4; ++j) {
                acc[i][j] = __builtin_amdgcn_mfma_f32_16x16x32_f16(ah, bh[j], acc[i][j], 0, 0, 0);
                acc[i][j] = __builtin_amdgcn_mfma_f32_16x16x32_f16(al, bh[j], acc[i][j], 0, 0, 0);
            }
        }
    };

    STAGE(0, 0);
    __syncthreads();
#pragma unroll
    for (int t = 0; t < 16; t += 2) {
        if (t + 1 < 16) STAGE(1, t + 1);
        COMPUTE(0);
        __syncthreads();
        if (t + 2 < 16) STAGE(0, t + 2);
        COMPUTE(1);
        __syncthreads();
    }

    // ---------------- epilogue: per-row top2 over this block's 128 cols ------
    unsigned long long* top2p = reinterpret_cast<unsigned long long*>(&sm[0][0][0]); // [128][2][2]
    float w2v[4];
#pragma unroll
    for (int j = 0; j < 4; ++j) w2v[j] = w2[hn0 + wc * 64 + j * 16 + (lane & 15)];

#pragma unroll
    for (int i = 0; i < 4; ++i) {
#pragma unroll
        for (int r = 0; r < 4; ++r) {
            unsigned long long k1 = ~0ull, k2 = ~0ull;
#pragma unroll
            for (int j = 0; j < 4; ++j) {
                float s = fmaf(-2.f, acc[i][j][r], w2v[j]);
                unsigned long long key = packkey(s, hn0 + wc * 64 + j * 16 + (lane & 15));
                if (key < k1) { k2 = k1; k1 = key; }
                else if (key < k2) { k2 = key; }
            }
#pragma unroll
            for (int m = 1; m < 16; m <<= 1) {
                unsigned long long o1 = shfl_xor_u64(k1, m);
                unsigned long long o2 = shfl_xor_u64(k2, m);
                unsigned long long n1 = u64min(k1, o1);
                unsigned long long mx = k1 < o1 ? o1 : k1;
                unsigned long long mn = u64min(k2, o2);
                k1 = n1;
                k2 = u64min(mx, mn);
            }
            if ((lane & 15) == 0) {
                int rl = wr * 64 + i * 16 + (lane >> 4) * 4 + r;
                top2p[(rl * 2 + wc) * 2 + 0] = k1;
                top2p[(rl * 2 + wc) * 2 + 1] = k2;
            }
        }
    }
    __syncthreads();
    if (tid < 128) {
        unsigned long long a1 = top2p[(tid * 2 + 0) * 2 + 0];
        unsigned long long a2 = top2p[(tid * 2 + 0) * 2 + 1];
        unsigned long long b1 = top2p[(tid * 2 + 1) * 2 + 0];
        unsigned long long b2 = top2p[(tid * 2 + 1) * 2 + 1];
        unsigned long long r1 = u64min(a1, b1);
        unsigned long long mx = a1 < b1 ? b1 : a1;
        unsigned long long r2 = u64min(mx, u64min(a2, b2));
        blocktop[(size_t)(bm0 + tid) * kNHB + hb] = (ulonglong2){r1, r2};
    }
}

// ---------------- finish: certify / exact-fp32 rescan + gather --------------
__global__ __launch_bounds__(256) void finish_kernel(
    const float* __restrict__ x, const float* __restrict__ W,
    const float* __restrict__ w2, const ulonglong2* __restrict__ blocktop,
    const float* __restrict__ Gf, const float* __restrict__ Gr,
    float* __restrict__ out)
{
    const int tid = threadIdx.x;
    const int b = blockIdx.x;
    __shared__ float xs[kD];
    __shared__ unsigned long long red[256];
    __shared__ unsigned long long sv1, sv2;
    __shared__ unsigned char cand[kNHB];

    if (tid < 128)
        reinterpret_cast<float4*>(xs)[tid] =
            reinterpret_cast<const float4*>(x + (size_t)b * kD)[tid];

    ulonglong2 t12;
    if (tid < kNHB) t12 = blocktop[(size_t)b * kNHB + tid];
    else            t12 = (ulonglong2){~0ull, ~0ull};

    red[tid] = (tid < kNHB) ? t12.x : ~0ull;
    __syncthreads();
    for (int s = 128; s > 0; s >>= 1) {
        if (tid < s) red[tid] = u64min(red[tid], red[tid + s]);
        __syncthreads();
    }
    if (tid == 0) sv1 = red[0];
    __syncthreads();
    const unsigned long long v1k = sv1;
    const float v1s = unpacks(v1k);
    const int b1hb = ((int)(unsigned)(v1k & 0xFFFFFFFFu)) >> 7;

    red[tid] = (tid < kNHB) ? ((tid == b1hb) ? t12.y : t12.x) : ~0ull;
    __syncthreads();
    for (int s = 128; s > 0; s >>= 1) {
        if (tid < s) red[tid] = u64min(red[tid], red[tid + s]);
        __syncthreads();
    }
    if (tid == 0) sv2 = red[0];
    __syncthreads();
    const float v2s = unpacks(sv2);

    int idx;
    if (v2s - v1s > kMargin) {          // certified (block-uniform branch)
        idx = (int)(unsigned)(v1k & 0xFFFFFFFFu);
    } else {
        // uncertain: exact fp32 scan of candidate blocks (round-1 order)
        if (tid < kNHB) cand[tid] = (unpacks(t12.x) <= v1s + kMargin) ? 1 : 0;
        __syncthreads();
        unsigned long long bestk = ~0ull;
        for (int hb = 0; hb < kNHB; ++hb) {
            if (!cand[hb]) continue;
            if (tid < 128) {
                int h = hb * 128 + tid;
                const float4* wr = reinterpret_cast<const float4*>(W + (size_t)h * kD);
                float dot = 0.f;
                for (int k = 0; k < kD / 4; ++k) {
                    float4 wvv = wr[k];
                    dot = fmaf(xs[k * 4 + 0], wvv.x, dot);
                    dot = fmaf(xs[k * 4 + 1], wvv.y, dot);
                    dot = fmaf(xs[k * 4 + 2], wvv.z, dot);
                    dot = fmaf(xs[k * 4 + 3], wvv.w, dot);
                }
                float s = fmaf(-2.f, dot, w2[h]);
                bestk = u64min(bestk, packkey(s, h));
            }
        }
        red[tid] = bestk;
        __syncthreads();
        for (int s = 128; s > 0; s >>= 1) {
            if (tid < s) red[tid] = u64min(red[tid], red[tid + s]);
            __syncthreads();
        }
        idx = (int)(unsigned)(red[0] & 0xFFFFFFFFu);
    }

    float* out0 = out;                            // (B, O)
    float* out1 = out + (size_t)kB * kO;          // (B, D)
    float* outw = out + (size_t)kB * (kO + kD);   // (B,)
    for (int o = tid; o < kO; o += 256)
        out0[(size_t)b * kO + o] = Gf[(size_t)o * kH + idx];
    for (int d = tid; d < kD; d += 256)
        out1[(size_t)b * kD + d] = Gr[(size_t)d * kH + idx];
    if (tid == 0) outw[b] = (float)idx;
}

extern "C" void kernel_launch(void* const* d_in, const int* in_sizes, int n_in,
                              void* d_out, int out_size, void* d_ws, size_t ws_size,
                              hipStream_t stream) {
    const float* x  = (const float*)d_in[0];
    const float* W  = (const float*)d_in[1];
    const float* Gf = (const float*)d_in[2];
    const float* Gr = (const float*)d_in[3];
    float* out = (float*)d_out;

    char* ws = (char*)d_ws;
    _Float16* xhi = (_Float16*)(ws + OFF_XHI);
    _Float16* xlo = (_Float16*)(ws + OFF_XLO);
    _Float16* whi = (_Float16*)(ws + OFF_WHI);
    float* w2 = (float*)(ws + OFF_W2);
    ulonglong2* blocktop = (ulonglong2*)(ws + OFF_BT);

    hipLaunchKernelGGL(split_kernel, dim3(kB * kD / (256 * 8)), dim3(256), 0, stream, x, xhi, xlo);
    hipLaunchKernelGGL(splitw_w2_kernel, dim3(kH / 4), dim3(256), 0, stream, W, whi, w2);
    hipLaunchKernelGGL(gemm_argmin_mfma, dim3(8192), dim3(256), 0, stream,
                       xhi, xlo, whi, w2, blocktop);
    hipLaunchKernelGGL(finish_kernel, dim3(kB), dim3(256), 0, stream,
                       x, W, w2, blocktop, Gf, Gr, out);
}

// Round 4
// 556.157 us; speedup vs baseline: 3.1437x; 1.2406x over previous
//
#include <hip/hip_runtime.h>
#include <stdint.h>

constexpr int kB = 8192;
constexpr int kD = 512;
constexpr int kH = 16384;
constexpr int kO = 1000;
constexpr int kNHB = kH / 128;          // 128 h-blocks
constexpr float kMargin = 0.08f;        // > 2*e_max (e_max ~0.025 for 2-term split)

typedef _Float16 half8v __attribute__((ext_vector_type(8)));
typedef _Float16 half4v __attribute__((ext_vector_type(4)));
typedef float float4v __attribute__((ext_vector_type(4)));

// ---------------------------------------------------------------------------
// ws layout (bytes):
//   OFF_XHI : f16 x_hi [8192*512]              (8 MB)
//   OFF_XLO : f16 x_lo                         (8 MB)
//   OFF_WHI : f16 w_hi [16384*512]             (16 MB)
//   OFF_W2  : f32 w2 [16384]                   (64 KB)
//   OFF_BT  : ulonglong2 blocktop [8192][128]  (16 MB)
//   OFF_GFT : f32 GfT [16384][1000]            (65.5 MB)
//   OFF_GRT : f32 GrT [16384][512]             (33.6 MB)
// total ~143 MB (fallback path if ws_size smaller)
// ---------------------------------------------------------------------------
constexpr size_t OFF_XHI = 0;
constexpr size_t OFF_XLO = OFF_XHI + (size_t)kB * kD * 2;
constexpr size_t OFF_WHI = OFF_XLO + (size_t)kB * kD * 2;
constexpr size_t OFF_W2  = OFF_WHI + (size_t)kH * kD * 2;
constexpr size_t OFF_BT  = OFF_W2 + 65536;
constexpr size_t OFF_GFT = OFF_BT + (size_t)kB * kNHB * 16;
constexpr size_t OFF_GRT = OFF_GFT + (size_t)kH * kO * 4;
constexpr size_t WS_NEED = OFF_GRT + (size_t)kH * kD * 4;

__device__ inline unsigned long long packkey(float s, int h) {
    unsigned u = __float_as_uint(s);
    u ^= (u & 0x80000000u) ? 0xFFFFFFFFu : 0x80000000u;
    return ((unsigned long long)u << 32) | (unsigned)h;
}
__device__ inline float unpacks(unsigned long long k) {
    unsigned u = (unsigned)(k >> 32);
    u ^= (u & 0x80000000u) ? 0x80000000u : 0xFFFFFFFFu;
    return __uint_as_float(u);
}
__device__ inline unsigned long long shfl_xor_u64(unsigned long long v, int m) {
    unsigned lo = (unsigned)v, hi = (unsigned)(v >> 32);
    lo = __shfl_xor(lo, m, 64);
    hi = __shfl_xor(hi, m, 64);
    return ((unsigned long long)hi << 32) | lo;
}
__device__ inline unsigned long long u64min(unsigned long long a, unsigned long long b) {
    return a < b ? a : b;
}

template <typename T>
__device__ inline void gload_lds16(const T* g, T* l) {
    __builtin_amdgcn_global_load_lds(
        (const __attribute__((address_space(1))) uint32_t*)g,
        (__attribute__((address_space(3))) uint32_t*)l, 16, 0, 0);
}

// --------------------------- split x: f32 -> f16 hi/lo ----------------------
__global__ __launch_bounds__(256) void split_kernel(const float* __restrict__ src,
                                                    _Float16* __restrict__ hi,
                                                    _Float16* __restrict__ lo) {
    size_t i = (size_t)blockIdx.x * 256 + threadIdx.x;   // 8 elems per thread
    const float4* s4 = reinterpret_cast<const float4*>(src);
    float4 a = s4[i * 2], b = s4[i * 2 + 1];
    float v[8] = {a.x, a.y, a.z, a.w, b.x, b.y, b.z, b.w};
    half8v h, l;
#pragma unroll
    for (int e = 0; e < 8; ++e) {
        _Float16 hh = (_Float16)v[e];
        h[e] = hh;
        l[e] = (_Float16)(v[e] - (float)hh);
    }
    *reinterpret_cast<half8v*>(hi + i * 8) = h;
    *reinterpret_cast<half8v*>(lo + i * 8) = l;
}

// ------------------ split W (hi only) + fused w2 (round-1 order) ------------
__global__ __launch_bounds__(256) void splitw_w2_kernel(const float* __restrict__ W,
                                                        _Float16* __restrict__ whi,
                                                        float* __restrict__ w2) {
    int lane = threadIdx.x & 63;
    int wv   = threadIdx.x >> 6;
    int row  = blockIdx.x * 4 + wv;
    const float4* Wr = reinterpret_cast<const float4*>(W + (size_t)row * kD);
    float s = 0.f;
#pragma unroll
    for (int i = 0; i < 2; ++i) {
        float4 v = Wr[lane + i * 64];
        s += v.x * v.x + v.y * v.y + v.z * v.z + v.w * v.w;
        half4v h = {(_Float16)v.x, (_Float16)v.y, (_Float16)v.z, (_Float16)v.w};
        *reinterpret_cast<half4v*>(whi + (size_t)row * kD + i * 256 + lane * 4) = h;
    }
#pragma unroll
    for (int off = 32; off; off >>= 1) s += __shfl_xor(s, off, 64);
    if (lane == 0) w2[row] = s;
}

// ------------------ 32x32 LDS-tiled transpose: src[R][C] -> dst[C][R] -------
__global__ __launch_bounds__(256) void transpose_kernel(const float* __restrict__ src,
                                                        float* __restrict__ dst,
                                                        int R, int C) {
    __shared__ float s[32][33];
    const int tx = threadIdx.x & 31;
    const int ty = threadIdx.x >> 5;       // 0..7
    const int c0 = blockIdx.x * 32;
    const int r0 = blockIdx.y * 32;
#pragma unroll
    for (int i = 0; i < 4; ++i) {
        int r = r0 + ty + i * 8;
        if (r < R) s[ty + i * 8][tx] = src[(size_t)r * C + c0 + tx];
    }
    __syncthreads();
#pragma unroll
    for (int i = 0; i < 4; ++i) {
        int c = c0 + ty + i * 8;
        if (r0 + tx < R) dst[(size_t)c * R + r0 + tx] = s[tx][ty + i * 8];
    }
}

// --------------------------- MFMA GEMM + per-block top2 ---------------------
// 128x128 tile, BK=32, 4 waves (2x2), 2-product split-f16, dbuf, XOR-swizzled LDS.
__global__ __launch_bounds__(256) void gemm_argmin_mfma(
    const _Float16* __restrict__ xhi, const _Float16* __restrict__ xlo,
    const _Float16* __restrict__ whi,
    const float* __restrict__ w2, ulonglong2* __restrict__ blocktop)
{
    __shared__ __align__(16) _Float16 sm[2][3][4096];   // [buf][Ah,Al,Bh][128 rows * 32]

    const int tid  = threadIdx.x;
    const int lane = tid & 63;
    const int wv   = tid >> 6;
    const int wr   = wv >> 1, wc = wv & 1;

    // XCD-aware swizzle (8192 % 8 == 0 -> bijective)
    int bid = blockIdx.x;
    int swz = (bid & 7) * (8192 / 8) + (bid >> 3);
    const int hb  = swz & 127;
    const int mb  = swz >> 7;
    const int bm0 = mb * 128, hn0 = hb * 128;

    float4v acc[4][4];
#pragma unroll
    for (int i = 0; i < 4; ++i)
#pragma unroll
        for (int j = 0; j < 4; ++j) acc[i][j] = (float4v){0.f, 0.f, 0.f, 0.f};

    // staging coords: each gload_lds16 stages 16 rows x 32 f16 (64 lanes x 16B)
    const int srow = lane >> 2;        // row within 16-row chunk
    const int sch  = lane & 3;         // dest 16B chunk within 64B row

    auto STAGE = [&](int bf, int step) {
        const int kt = step * 32;
#pragma unroll
        for (int h2 = 0; h2 < 2; ++h2) {
            const int r0 = wv * 32 + h2 * 16;            // wave-uniform
            const int r  = r0 + srow;                    // row within 128-tile
            const int cs = sch ^ ((r >> 1) & 3);         // pre-swizzled source chunk
            const size_t ka = (size_t)kt + cs * 8;
            gload_lds16(xhi + (size_t)(bm0 + r) * kD + ka, &sm[bf][0][r0 * 32]);
            gload_lds16(xlo + (size_t)(bm0 + r) * kD + ka, &sm[bf][1][r0 * 32]);
            gload_lds16(whi + (size_t)(hn0 + r) * kD + ka, &sm[bf][2][r0 * 32]);
        }
    };
    auto COMPUTE = [&](int bf) {
        half8v bh[4];
#pragma unroll
        for (int j = 0; j < 4; ++j) {
            const int row = wc * 64 + j * 16 + (lane & 15);
            const int cs  = (lane >> 4) ^ ((row >> 1) & 3);
            bh[j] = *reinterpret_cast<const half8v*>(&sm[bf][2][row * 32 + cs * 8]);
        }
#pragma unroll
        for (int i = 0; i < 4; ++i) {
            const int arow = wr * 64 + i * 16 + (lane & 15);
            const int acs  = (lane >> 4) ^ ((arow >> 1) & 3);
            half8v ah = *reinterpret_cast<const half8v*>(&sm[bf][0][arow * 32 + acs * 8]);
            half8v al = *reinterpret_cast<const half8v*>(&sm[bf][1][arow * 32 + acs * 8]);
#pragma unroll
            for (int j = 0; j < 4; ++j) {
                acc[i][j] = __builtin_amdgcn_mfma_f32_16x16x32_f16(ah, bh[j], acc[i][j], 0, 0, 0);
                acc[i][j] = __builtin_amdgcn_mfma_f32_16x16x32_f16(al, bh[j], acc[i][j], 0, 0, 0);
            }
        }
    };

    STAGE(0, 0);
    __syncthreads();
#pragma unroll
    for (int t = 0; t < 16; t += 2) {
        if (t + 1 < 16) STAGE(1, t + 1);
        COMPUTE(0);
        __syncthreads();
        if (t + 2 < 16) STAGE(0, t + 2);
        COMPUTE(1);
        __syncthreads();
    }

    // ---------------- epilogue: per-row top2 over this block's 128 cols ------
    unsigned long long* top2p = reinterpret_cast<unsigned long long*>(&sm[0][0][0]); // [128][2][2]
    float w2v[4];
#pragma unroll
    for (int j = 0; j < 4; ++j) w2v[j] = w2[hn0 + wc * 64 + j * 16 + (lane & 15)];

#pragma unroll
    for (int i = 0; i < 4; ++i) {
#pragma unroll
        for (int r = 0; r < 4; ++r) {
            unsigned long long k1 = ~0ull, k2 = ~0ull;
#pragma unroll
            for (int j = 0; j < 4; ++j) {
                float s = fmaf(-2.f, acc[i][j][r], w2v[j]);
                unsigned long long key = packkey(s, hn0 + wc * 64 + j * 16 + (lane & 15));
                if (key < k1) { k2 = k1; k1 = key; }
                else if (key < k2) { k2 = key; }
            }
#pragma unroll
            for (int m = 1; m < 16; m <<= 1) {
                unsigned long long o1 = shfl_xor_u64(k1, m);
                unsigned long long o2 = shfl_xor_u64(k2, m);
                unsigned long long n1 = u64min(k1, o1);
                unsigned long long mx = k1 < o1 ? o1 : k1;
                unsigned long long mn = u64min(k2, o2);
                k1 = n1;
                k2 = u64min(mx, mn);
            }
            if ((lane & 15) == 0) {
                int rl = wr * 64 + i * 16 + (lane >> 4) * 4 + r;
                top2p[(rl * 2 + wc) * 2 + 0] = k1;
                top2p[(rl * 2 + wc) * 2 + 1] = k2;
            }
        }
    }
    __syncthreads();
    if (tid < 128) {
        unsigned long long a1 = top2p[(tid * 2 + 0) * 2 + 0];
        unsigned long long a2 = top2p[(tid * 2 + 0) * 2 + 1];
        unsigned long long b1 = top2p[(tid * 2 + 1) * 2 + 0];
        unsigned long long b2 = top2p[(tid * 2 + 1) * 2 + 1];
        unsigned long long r1 = u64min(a1, b1);
        unsigned long long mx = a1 < b1 ? b1 : a1;
        unsigned long long r2 = u64min(mx, u64min(a2, b2));
        blocktop[(size_t)(bm0 + tid) * kNHB + hb] = (ulonglong2){r1, r2};
    }
}

// ---------------- finish: certify / exact-fp32 rescan + gather --------------
__global__ __launch_bounds__(256) void finish_kernel(
    const float* __restrict__ x, const float* __restrict__ W,
    const float* __restrict__ w2, const ulonglong2* __restrict__ blocktop,
    const float* __restrict__ Gf, const float* __restrict__ Gr,
    const float* __restrict__ GfT, const float* __restrict__ GrT,
    int useT, float* __restrict__ out)
{
    const int tid = threadIdx.x;
    const int b = blockIdx.x;
    __shared__ float xs[kD];
    __shared__ unsigned long long red[256];
    __shared__ unsigned long long sv1, sv2;
    __shared__ unsigned char cand[kNHB];

    if (tid < 128)
        reinterpret_cast<float4*>(xs)[tid] =
            reinterpret_cast<const float4*>(x + (size_t)b * kD)[tid];

    ulonglong2 t12;
    if (tid < kNHB) t12 = blocktop[(size_t)b * kNHB + tid];
    else            t12 = (ulonglong2){~0ull, ~0ull};

    red[tid] = (tid < kNHB) ? t12.x : ~0ull;
    __syncthreads();
    for (int s = 128; s > 0; s >>= 1) {
        if (tid < s) red[tid] = u64min(red[tid], red[tid + s]);
        __syncthreads();
    }
    if (tid == 0) sv1 = red[0];
    __syncthreads();
    const unsigned long long v1k = sv1;
    const float v1s = unpacks(v1k);
    const int b1hb = ((int)(unsigned)(v1k & 0xFFFFFFFFu)) >> 7;

    red[tid] = (tid < kNHB) ? ((tid == b1hb) ? t12.y : t12.x) : ~0ull;
    __syncthreads();
    for (int s = 128; s > 0; s >>= 1) {
        if (tid < s) red[tid] = u64min(red[tid], red[tid + s]);
        __syncthreads();
    }
    if (tid == 0) sv2 = red[0];
    __syncthreads();
    const float v2s = unpacks(sv2);

    int idx;
    if (v2s - v1s > kMargin) {          // certified (block-uniform branch)
        idx = (int)(unsigned)(v1k & 0xFFFFFFFFu);
    } else {
        // uncertain: exact fp32 scan of candidate blocks (round-1 order)
        if (tid < kNHB) cand[tid] = (unpacks(t12.x) <= v1s + kMargin) ? 1 : 0;
        __syncthreads();
        unsigned long long bestk = ~0ull;
        for (int hb = 0; hb < kNHB; ++hb) {
            if (!cand[hb]) continue;
            if (tid < 128) {
                int h = hb * 128 + tid;
                const float4* wr = reinterpret_cast<const float4*>(W + (size_t)h * kD);
                float dot = 0.f;
                for (int k = 0; k < kD / 4; ++k) {
                    float4 wvv = wr[k];
                    dot = fmaf(xs[k * 4 + 0], wvv.x, dot);
                    dot = fmaf(xs[k * 4 + 1], wvv.y, dot);
                    dot = fmaf(xs[k * 4 + 2], wvv.z, dot);
                    dot = fmaf(xs[k * 4 + 3], wvv.w, dot);
                }
                float s = fmaf(-2.f, dot, w2[h]);
                bestk = u64min(bestk, packkey(s, h));
            }
        }
        red[tid] = bestk;
        __syncthreads();
        for (int s = 128; s > 0; s >>= 1) {
            if (tid < s) red[tid] = u64min(red[tid], red[tid + s]);
            __syncthreads();
        }
        idx = (int)(unsigned)(red[0] & 0xFFFFFFFFu);
    }

    float* out0 = out;                            // (B, O)
    float* out1 = out + (size_t)kB * kO;          // (B, D)
    float* outw = out + (size_t)kB * (kO + kD);   // (B,)
    if (useT) {                                   // coalesced row gather
        const float4* gfr = reinterpret_cast<const float4*>(GfT + (size_t)idx * kO);
        float4* o0 = reinterpret_cast<float4*>(out0 + (size_t)b * kO);
        for (int o = tid; o < kO / 4; o += 256) o0[o] = gfr[o];
        const float4* grr = reinterpret_cast<const float4*>(GrT + (size_t)idx * kD);
        float4* o1 = reinterpret_cast<float4*>(out1 + (size_t)b * kD);
        if (tid < kD / 4) o1[tid] = grr[tid];
    } else {                                      // fallback: column gather
        for (int o = tid; o < kO; o += 256)
            out0[(size_t)b * kO + o] = Gf[(size_t)o * kH + idx];
        for (int d = tid; d < kD; d += 256)
            out1[(size_t)b * kD + d] = Gr[(size_t)d * kH + idx];
    }
    if (tid == 0) outw[b] = (float)idx;
}

extern "C" void kernel_launch(void* const* d_in, const int* in_sizes, int n_in,
                              void* d_out, int out_size, void* d_ws, size_t ws_size,
                              hipStream_t stream) {
    const float* x  = (const float*)d_in[0];
    const float* W  = (const float*)d_in[1];
    const float* Gf = (const float*)d_in[2];
    const float* Gr = (const float*)d_in[3];
    float* out = (float*)d_out;

    char* ws = (char*)d_ws;
    _Float16* xhi = (_Float16*)(ws + OFF_XHI);
    _Float16* xlo = (_Float16*)(ws + OFF_XLO);
    _Float16* whi = (_Float16*)(ws + OFF_WHI);
    float* w2 = (float*)(ws + OFF_W2);
    ulonglong2* blocktop = (ulonglong2*)(ws + OFF_BT);
    float* GfT = (float*)(ws + OFF_GFT);
    float* GrT = (float*)(ws + OFF_GRT);
    const int useT = (ws_size >= WS_NEED) ? 1 : 0;

    hipLaunchKernelGGL(split_kernel, dim3(kB * kD / (256 * 8)), dim3(256), 0, stream, x, xhi, xlo);
    hipLaunchKernelGGL(splitw_w2_kernel, dim3(kH / 4), dim3(256), 0, stream, W, whi, w2);
    if (useT) {
        hipLaunchKernelGGL(transpose_kernel, dim3(kH / 32, (kO + 31) / 32), dim3(256), 0, stream,
                           Gf, GfT, kO, kH);
        hipLaunchKernelGGL(transpose_kernel, dim3(kH / 32, kD / 32), dim3(256), 0, stream,
                           Gr, GrT, kD, kH);
    }
    hipLaunchKernelGGL(gemm_argmin_mfma, dim3(8192), dim3(256), 0, stream,
                       xhi, xlo, whi, w2, blocktop);
    hipLaunchKernelGGL(finish_kernel, dim3(kB), dim3(256), 0, stream,
                       x, W, w2, blocktop, Gf, Gr, GfT, GrT, useT, out);
}